// Round 3
// baseline (325.948 us; speedup 1.0000x reference)
//
#include <hip/hip_runtime.h>
#include <hip/hip_bf16.h>

// Cabasc: B=64, S=512, Ta=8, D=768
// Round 3: GEMM 256x128 block / 128x64 wave tile (less LDS traffic per FLOP),
// fused pre-kernel (transpose+lens+v_a), fused softmax+vts, wider streaming grids.

#define NB 64
#define NS 512
#define ND 768
#define NTA 8

typedef __attribute__((ext_vector_type(8))) __bf16 bf16x8;
typedef __attribute__((ext_vector_type(4))) float f32x4;

// ---- workspace layout (bytes) ----
#define OFF_SCORES 0u           // NB*NS f32   = 131072
#define OFF_VS 131072u          // NB*ND f32   = 196608
#define OFF_VTS 327680u         // NB*ND f32
#define OFF_CTX 524288u         // NB*ND f32   (atomic accum)
#define OFF_U 720896u           // NB*ND f32   (pre-tanh v_ms accum)
#define ZERO_BYTES 917504u      // [0, 917504) zeroed each launch
#define OFF_VA 917504u          // NB*ND f32
#define OFF_LENS 1245184u       // mlenf[64] | inv_mlen[64] | inv_alen[64]
#define OFF_W1MT 1246208u       // ND*ND bf16 = 1179648
#define OFF_MP 2425856u         // NB*NS*ND bf16 = 50331648 (total ~52.8 MB)

__device__ __forceinline__ float fast_tanh(float x) {
  x = fminf(fmaxf(x, -15.f), 15.f);
  float t = __expf(2.f * x);
  return __fdividef(t - 1.f, t + 1.f);
}

__device__ __forceinline__ unsigned bfpack2(float a, float b) {
  unsigned ua = __float_as_uint(a), ub = __float_as_uint(b);
  ua = (ua + 0x7FFFu + ((ua >> 16) & 1u)) >> 16;
  ub = (ub + 0x7FFFu + ((ub >> 16) & 1u)) >> 16;
  return ua | (ub << 16);
}

__device__ __forceinline__ unsigned short bf16b(float f) {
  unsigned u = __float_as_uint(f);
  u = (u + 0x7FFFu + ((u >> 16) & 1u)) >> 16;
  return (unsigned short)u;
}

__device__ __forceinline__ void async_copy16(const void* g, void* l) {
  __builtin_amdgcn_global_load_lds(
      (const __attribute__((address_space(1))) void*)g,
      (__attribute__((address_space(3))) void*)l, 16, 0, 0);
}

// ---------- fused: W1_m transpose->bf16 (blocks 0..575) + lens/v_a (blocks 576..639) ----------
__global__ __launch_bounds__(256) void k_pre(const float* __restrict__ W1,
                                             unsigned short* __restrict__ w1mt,
                                             const int* __restrict__ ids,
                                             const int* __restrict__ tids,
                                             const float* __restrict__ aspect,
                                             float* __restrict__ v_a,
                                             float* __restrict__ lens) {
  int bid = blockIdx.x, tid = threadIdx.x;
  if (bid < 576) {
    __shared__ float tile[32][33];
    int bx = bid % 24, by = bid / 24;
    int tx = tid & 31, ty = tid >> 5;  // 32 x 8
    for (int j = 0; j < 32; j += 8)
      tile[ty + j][tx] = W1[(size_t)(by * 32 + ty + j) * ND + bx * 32 + tx];
    __syncthreads();
    for (int j = 0; j < 32; j += 8)
      w1mt[(size_t)(bx * 32 + ty + j) * ND + by * 32 + tx] = bf16b(tile[tx][ty + j]);
  } else {
    int b = bid - 576;
    __shared__ int red[256];
    __shared__ float sh_inva;
    int cnt = 0;
    for (int j = tid; j < NS; j += 256) cnt += (ids[b * NS + j] != 0);
    red[tid] = cnt;
    __syncthreads();
    for (int s = 128; s > 0; s >>= 1) {
      if (tid < s) red[tid] += red[tid + s];
      __syncthreads();
    }
    if (tid == 0) {
      int mlen = red[0];
      int acnt = 0;
      for (int t = 0; t < NTA; ++t) acnt += (tids[b * NTA + t] != 0);
      lens[b] = (float)mlen;
      lens[64 + b] = 1.0f / (float)mlen;
      float inva = 1.0f / (float)acnt;
      lens[128 + b] = inva;
      sh_inva = inva;
    }
    __syncthreads();
    float inva = sh_inva;
    for (int j = tid; j < ND; j += 256) {
      float s = 0.f;
      for (int t = 0; t < NTA; ++t) s += aspect[((size_t)b * NTA + t) * ND + j];
      v_a[b * ND + j] = s * inva;
    }
  }
}

// ---------- v_s (mean of memory) + m' = bf16(memory * loc), 32 rows/block ----------
__global__ __launch_bounds__(192) void k_vs_mprime(const float* __restrict__ memory,
                                                   const float* __restrict__ lens,
                                                   float* __restrict__ v_s,
                                                   unsigned short* __restrict__ mp) {
  int sc = blockIdx.x, b = blockIdx.y, tid = threadIdx.x;
  int d0 = tid * 4;
  float inv_mlen = lens[64 + b];
  float mlenf = lens[b];
  float s0 = 0, s1 = 0, s2 = 0, s3 = 0;
  for (int s = 0; s < 32; ++s) {
    int srow = sc * 32 + s;
    size_t row = (size_t)b * NS + srow;
    const float4 v = *(const float4*)(memory + row * ND + d0);
    s0 += v.x; s1 += v.y; s2 += v.z; s3 += v.w;
    float fs = (float)srow;
    float loc = (fs < mlenf) ? 1.0f - fs * inv_mlen : 1.0f;
    uint2 pk;
    pk.x = bfpack2(v.x * loc, v.y * loc);
    pk.y = bfpack2(v.z * loc, v.w * loc);
    *(uint2*)(mp + row * ND + d0) = pk;
  }
  float* p = v_s + b * ND + d0;
  atomicAdd(p + 0, s0 * inv_mlen);
  atomicAdd(p + 1, s1 * inv_mlen);
  atomicAdd(p + 2, s2 * inv_mlen);
  atomicAdd(p + 3, s3 * inv_mlen);
}

// ---------- ctx += partial([v_a;v_s] @ [W1_a;W1_s]), split-K over 4 ----------
__global__ __launch_bounds__(128) void k_ctx(const float* __restrict__ W1,
                                             const float* __restrict__ v_a,
                                             const float* __restrict__ v_s,
                                             float* __restrict__ ctx) {
  int et = blockIdx.x, b = blockIdx.y, dc = blockIdx.z, tid = threadIdx.x;
  __shared__ float vbuf[384];
  for (int j = tid; j < 384; j += 128) {
    int k = dc * 384 + j;
    vbuf[j] = (k < ND) ? v_a[b * ND + k] : v_s[b * ND + (k - ND)];
  }
  __syncthreads();
  int e = et * 128 + tid;
  float acc = 0.f;
  const float* Wk = W1 + (size_t)(ND + dc * 384) * ND + e;
#pragma unroll 8
  for (int j = 0; j < 384; ++j) acc += vbuf[j] * Wk[(size_t)j * ND];
  atomicAdd(&ctx[b * ND + e], acc);
}

// ---------- big GEMM: scores[row] += sum_e tanh((m'@W1_m)[row,e]+ctx+b1)*w2[e] ----------
// 256x128 block tile, 128x64 wave tile (8x4 of 16x16), BK=64, global_load_lds w=16.
// LDS row = 128 B = 8 chunks; XOR swizzle phys_q = q ^ (row&7) on the global side.
__global__ __launch_bounds__(256, 2) void k_gemm_scores(const unsigned short* __restrict__ mp,
                                                        const unsigned short* __restrict__ w1mt,
                                                        const float* __restrict__ ctx,
                                                        const float* __restrict__ b1,
                                                        const float* __restrict__ w2,
                                                        float* __restrict__ scores) {
  __shared__ char lds[49152];
  char* ldsA = lds;          // 256 rows x 128 B = 32 KB
  char* ldsB = lds + 32768;  // 128 rows x 128 B = 16 KB
  const int tid = threadIdx.x;
  const int wave = tid >> 6, lane = tid & 63;
  const int et = blockIdx.x, rt = blockIdx.y;
  const int row0 = rt * 256, n0 = et * 128;
  const int b = row0 >> 9;  // 256 | 512: tile never crosses a batch
  const int wm = wave & 1, wn = wave >> 1;

  // staging: each issue = 64 lanes x 16 B = 8 rows x 8 chunks, swizzled source
  const int lrow = lane >> 3;
  const int qlog = (lane & 7) ^ lrow;
  const char* Abase = (const char*)mp + (size_t)(row0 + lrow) * (ND * 2) + qlog * 16;
  const char* Bbase = (const char*)w1mt + (size_t)(n0 + lrow) * (ND * 2) + qlog * 16;

  f32x4 acc[8][4];
#pragma unroll
  for (int i = 0; i < 8; ++i)
#pragma unroll
    for (int t = 0; t < 4; ++t) acc[i][t] = (f32x4){0.f, 0.f, 0.f, 0.f};

  const int q2 = lane >> 4, c = lane & 15;
  int offA0[8], offB0[4];
#pragma unroll
  for (int i = 0; i < 8; ++i) {
    int ml = wm * 128 + i * 16 + c;
    offA0[i] = ml * 128 + ((q2 ^ (ml & 7)) * 16);
  }
#pragma unroll
  for (int t = 0; t < 4; ++t) {
    int nl = wn * 64 + t * 16 + c;
    offB0[t] = nl * 128 + ((q2 ^ (nl & 7)) * 16);
  }
  // kk=1 chunk = (q2+4) ^ (row&7) = (q2 ^ (row&7)) ^ 4  ->  byte offset ^ 64

  for (int kb = 0; kb < ND * 2; kb += 128) {  // 12 K-steps of 64 k
#pragma unroll
    for (int i = 0; i < 8; ++i) {
      int g = wave * 8 + i;
      async_copy16(Abase + (size_t)g * 8 * (ND * 2) + kb, ldsA + g * 1024);
    }
#pragma unroll
    for (int i = 0; i < 4; ++i) {
      int g = wave * 4 + i;
      async_copy16(Bbase + (size_t)g * 8 * (ND * 2) + kb, ldsB + g * 1024);
    }
    __syncthreads();
#pragma unroll
    for (int kk = 0; kk < 2; ++kk) {
      const int x = kk * 64;
      bf16x8 bfrag[4];
#pragma unroll
      for (int t = 0; t < 4; ++t) bfrag[t] = *(const bf16x8*)(ldsB + (offB0[t] ^ x));
#pragma unroll
      for (int i = 0; i < 8; ++i) {
        bf16x8 afrag = *(const bf16x8*)(ldsA + (offA0[i] ^ x));
#pragma unroll
        for (int t = 0; t < 4; ++t)
          acc[i][t] = __builtin_amdgcn_mfma_f32_16x16x32_bf16(afrag, bfrag[t], acc[i][t], 0, 0, 0);
      }
    }
    __syncthreads();
  }

  // epilogue: C/D tile layout row = q2*4+r, col = c
  float ctxv[4], w2v[4];
#pragma unroll
  for (int t = 0; t < 4; ++t) {
    int n = n0 + wn * 64 + t * 16 + c;
    ctxv[t] = ctx[b * ND + n] + b1[n];
    w2v[t] = w2[n];
  }
#pragma unroll
  for (int i = 0; i < 8; ++i) {
#pragma unroll
    for (int r = 0; r < 4; ++r) {
      float s = 0.f;
#pragma unroll
      for (int t = 0; t < 4; ++t) s += fast_tanh(acc[i][t][r] + ctxv[t]) * w2v[t];
      s += __shfl_xor(s, 1, 64);
      s += __shfl_xor(s, 2, 64);
      s += __shfl_xor(s, 4, 64);
      s += __shfl_xor(s, 8, 64);
      if (c == 0) atomicAdd(&scores[row0 + wm * 128 + i * 16 + q2 * 4 + r], s);
    }
  }
}

// ---------- fused softmax + v_ts: each block recomputes softmax stats, 32 rows ----------
__global__ __launch_bounds__(192) void k_vts_sm(const unsigned short* __restrict__ mp,
                                                const float* __restrict__ scores,
                                                float* __restrict__ v_ts) {
  int sc = blockIdx.x, b = blockIdx.y, tid = threadIdx.x;
  int wid = tid >> 6, lane = tid & 63;
  __shared__ float sm[3], ss[3];
  __shared__ float al[32];
  float v[3];
#pragma unroll
  for (int k = 0; k < 3; ++k) {
    int j = tid + k * 192;
    v[k] = (j < NS) ? scores[b * NS + j] : -1e30f;
  }
  float m = fmaxf(fmaxf(v[0], v[1]), v[2]);
  for (int off = 1; off < 64; off <<= 1) m = fmaxf(m, __shfl_xor(m, off, 64));
  if (lane == 0) sm[wid] = m;
  __syncthreads();
  float M = fmaxf(fmaxf(sm[0], sm[1]), sm[2]);
  float e = 0.f;
#pragma unroll
  for (int k = 0; k < 3; ++k)
    if (tid + k * 192 < NS) e += __expf(v[k] - M);
  for (int off = 1; off < 64; off <<= 1) e += __shfl_xor(e, off, 64);
  if (lane == 0) ss[wid] = e;
  __syncthreads();
  float invS = 1.0f / (ss[0] + ss[1] + ss[2]);
  if (tid < 32) al[tid] = __expf(scores[b * NS + sc * 32 + tid] - M) * invS;
  __syncthreads();

  int d0 = tid * 4;
  float a0 = 0, a1 = 0, a2 = 0, a3 = 0;
  for (int s = 0; s < 32; ++s) {
    size_t row = (size_t)b * NS + sc * 32 + s;
    uint2 pk = *(const uint2*)(mp + row * ND + d0);
    float a = al[s];
    a0 += a * __uint_as_float(pk.x << 16);
    a1 += a * __uint_as_float(pk.x & 0xFFFF0000u);
    a2 += a * __uint_as_float(pk.y << 16);
    a3 += a * __uint_as_float(pk.y & 0xFFFF0000u);
  }
  float* p = v_ts + b * ND + d0;
  atomicAdd(p + 0, a0);
  atomicAdd(p + 1, a1);
  atomicAdd(p + 2, a2);
  atomicAdd(p + 3, a3);
}

// ---------- u += partial((v_ts+v_s) @ Wm), split-K over 4 ----------
__global__ __launch_bounds__(128) void k_final1(const float* __restrict__ v_ts,
                                                const float* __restrict__ v_s,
                                                const float* __restrict__ Wm,
                                                float* __restrict__ u) {
  int et = blockIdx.x, b = blockIdx.y, dc = blockIdx.z, tid = threadIdx.x;
  __shared__ float vbuf[192];
  for (int j = tid; j < 192; j += 128) {
    int d = dc * 192 + j;
    vbuf[j] = v_ts[b * ND + d] + v_s[b * ND + d];
  }
  __syncthreads();
  int e = et * 128 + tid;
  float acc = 0.f;
  const float* Wk = Wm + (size_t)(dc * 192) * ND + e;
#pragma unroll 8
  for (int j = 0; j < 192; ++j) acc += vbuf[j] * Wk[(size_t)j * ND];
  atomicAdd(&u[b * ND + e], acc);
}

// ---------- logits = tanh(u+bm) @ Wd + bd ----------
__global__ __launch_bounds__(256) void k_final2(const float* __restrict__ u,
                                                const float* __restrict__ bm,
                                                const float* __restrict__ Wd,
                                                const float* __restrict__ bd,
                                                float* __restrict__ out) {
  int b = blockIdx.x, tid = threadIdx.x;
  int wid = tid >> 6, lane = tid & 63;
  __shared__ float red[4][3];
  float p0 = 0, p1 = 0, p2 = 0;
  for (int e = tid; e < ND; e += 256) {
    float vm = fast_tanh(u[b * ND + e] + bm[e]);
    p0 += vm * Wd[e * 3 + 0];
    p1 += vm * Wd[e * 3 + 1];
    p2 += vm * Wd[e * 3 + 2];
  }
  for (int off = 1; off < 64; off <<= 1) {
    p0 += __shfl_xor(p0, off, 64);
    p1 += __shfl_xor(p1, off, 64);
    p2 += __shfl_xor(p2, off, 64);
  }
  if (lane == 0) { red[wid][0] = p0; red[wid][1] = p1; red[wid][2] = p2; }
  __syncthreads();
  if (tid == 0) {
    out[b * 3 + 0] = red[0][0] + red[1][0] + red[2][0] + red[3][0] + bd[0];
    out[b * 3 + 1] = red[0][1] + red[1][1] + red[2][1] + red[3][1] + bd[1];
    out[b * 3 + 2] = red[0][2] + red[1][2] + red[2][2] + red[3][2] + bd[2];
  }
}

extern "C" void kernel_launch(void* const* d_in, const int* in_sizes, int n_in,
                              void* d_out, int out_size, void* d_ws, size_t ws_size,
                              hipStream_t stream) {
  const float* memory = (const float*)d_in[0];
  const float* aspect = (const float*)d_in[1];
  const int* ids = (const int*)d_in[2];
  const int* tids = (const int*)d_in[3];
  const float* W1 = (const float*)d_in[4];
  const float* b1 = (const float*)d_in[5];
  const float* w2 = (const float*)d_in[6];
  const float* Wm = (const float*)d_in[7];
  const float* bm = (const float*)d_in[8];
  const float* Wd = (const float*)d_in[9];
  const float* bd = (const float*)d_in[10];
  float* out = (float*)d_out;

  char* ws = (char*)d_ws;
  float* scores = (float*)(ws + OFF_SCORES);
  float* v_s = (float*)(ws + OFF_VS);
  float* v_ts = (float*)(ws + OFF_VTS);
  float* ctx = (float*)(ws + OFF_CTX);
  float* u = (float*)(ws + OFF_U);
  float* v_a = (float*)(ws + OFF_VA);
  float* lens = (float*)(ws + OFF_LENS);
  unsigned short* w1mt = (unsigned short*)(ws + OFF_W1MT);
  unsigned short* mp = (unsigned short*)(ws + OFF_MP);

  hipMemsetAsync(ws, 0, ZERO_BYTES, stream);

  k_pre<<<640, 256, 0, stream>>>(W1, w1mt, ids, tids, aspect, v_a, lens);
  k_vs_mprime<<<dim3(16, NB), 192, 0, stream>>>(memory, lens, v_s, mp);
  k_ctx<<<dim3(6, NB, 4), 128, 0, stream>>>(W1, v_a, v_s, ctx);
  k_gemm_scores<<<dim3(6, 128), 256, 0, stream>>>(mp, w1mt, ctx, b1, w2, scores);
  k_vts_sm<<<dim3(16, NB), 192, 0, stream>>>(mp, scores, v_ts);
  k_final1<<<dim3(6, NB, 4), 128, 0, stream>>>(v_ts, v_s, Wm, u);
  k_final2<<<NB, 256, 0, stream>>>(u, bm, Wd, bd, out);
}

// Round 4
// 324.632 us; speedup vs baseline: 1.0041x; 1.0041x over previous
//
#include <hip/hip_runtime.h>
#include <hip/hip_bf16.h>

// Cabasc: B=64, S=512, Ta=8, D=768
// Round 4: revert GEMM to round-2 shape (128x128/BK=64) + XCD-locality swizzle;
// batched-GEMV ctx/final1 (W read once per 8 batches); memset folded into k_pre.

#define NB 64
#define NS 512
#define ND 768
#define NTA 8

typedef __attribute__((ext_vector_type(8))) __bf16 bf16x8;
typedef __attribute__((ext_vector_type(4))) float f32x4;

// ---- workspace layout (bytes) ----
#define OFF_SCORES 0u           // NB*NS f32   = 131072
#define OFF_VS 131072u          // NB*ND f32   = 196608
#define OFF_VTS 327680u         // NB*ND f32
#define OFF_CTX 524288u         // NB*ND f32   (atomic accum)
#define OFF_U 720896u           // NB*ND f32   (pre-tanh v_ms accum)
#define ZERO_BYTES 917504u      // [0, 917504) zeroed by k_pre zero-blocks
#define OFF_VA 917504u          // NB*ND f32
#define OFF_LENS 1245184u       // mlenf[64] | inv_mlen[64] | inv_alen[64]
#define OFF_W1MT 1246208u       // ND*ND bf16 = 1179648
#define OFF_MP 2425856u         // NB*NS*ND bf16 = 50331648 (total ~52.8 MB)

__device__ __forceinline__ float fast_tanh(float x) {
  x = fminf(fmaxf(x, -15.f), 15.f);
  float t = __expf(2.f * x);
  return __fdividef(t - 1.f, t + 1.f);
}

__device__ __forceinline__ unsigned bfpack2(float a, float b) {
  unsigned ua = __float_as_uint(a), ub = __float_as_uint(b);
  ua = (ua + 0x7FFFu + ((ua >> 16) & 1u)) >> 16;
  ub = (ub + 0x7FFFu + ((ub >> 16) & 1u)) >> 16;
  return ua | (ub << 16);
}

__device__ __forceinline__ unsigned short bf16b(float f) {
  unsigned u = __float_as_uint(f);
  u = (u + 0x7FFFu + ((u >> 16) & 1u)) >> 16;
  return (unsigned short)u;
}

__device__ __forceinline__ void async_copy16(const void* g, void* l) {
  __builtin_amdgcn_global_load_lds(
      (const __attribute__((address_space(1))) void*)g,
      (__attribute__((address_space(3))) void*)l, 16, 0, 0);
}

// ---------- fused: W1_m transpose (0..575) + lens/v_a (576..639) + ws zeroing (640..863) ----------
__global__ __launch_bounds__(256) void k_pre(const float* __restrict__ W1,
                                             unsigned short* __restrict__ w1mt,
                                             const int* __restrict__ ids,
                                             const int* __restrict__ tids,
                                             const float* __restrict__ aspect,
                                             float* __restrict__ v_a,
                                             float* __restrict__ lens,
                                             char* __restrict__ zws) {
  int bid = blockIdx.x, tid = threadIdx.x;
  if (bid < 576) {
    __shared__ float tile[32][33];
    int bx = bid % 24, by = bid / 24;
    int tx = tid & 31, ty = tid >> 5;  // 32 x 8
    for (int j = 0; j < 32; j += 8)
      tile[ty + j][tx] = W1[(size_t)(by * 32 + ty + j) * ND + bx * 32 + tx];
    __syncthreads();
    for (int j = 0; j < 32; j += 8)
      w1mt[(size_t)(bx * 32 + ty + j) * ND + by * 32 + tx] = bf16b(tile[tx][ty + j]);
  } else if (bid < 640) {
    int b = bid - 576;
    __shared__ int red[256];
    __shared__ float sh_inva;
    int cnt = 0;
    for (int j = tid; j < NS; j += 256) cnt += (ids[b * NS + j] != 0);
    red[tid] = cnt;
    __syncthreads();
    for (int s = 128; s > 0; s >>= 1) {
      if (tid < s) red[tid] += red[tid + s];
      __syncthreads();
    }
    if (tid == 0) {
      int mlen = red[0];
      int acnt = 0;
      for (int t = 0; t < NTA; ++t) acnt += (tids[b * NTA + t] != 0);
      lens[b] = (float)mlen;
      lens[64 + b] = 1.0f / (float)mlen;
      float inva = 1.0f / (float)acnt;
      lens[128 + b] = inva;
      sh_inva = inva;
    }
    __syncthreads();
    float inva = sh_inva;
    for (int j = tid; j < ND; j += 256) {
      float s = 0.f;
      for (int t = 0; t < NTA; ++t) s += aspect[((size_t)b * NTA + t) * ND + j];
      v_a[b * ND + j] = s * inva;
    }
  } else {
    // zero the accumulator region: 224 blocks x 256 thr x 16 B = 917504 B
    uint4 z = {0u, 0u, 0u, 0u};
    *(uint4*)(zws + (size_t)(bid - 640) * 4096 + tid * 16) = z;
  }
}

// ---------- v_s (mean of memory) + m' = bf16(memory * loc), 32 rows/block ----------
__global__ __launch_bounds__(192) void k_vs_mprime(const float* __restrict__ memory,
                                                   const float* __restrict__ lens,
                                                   float* __restrict__ v_s,
                                                   unsigned short* __restrict__ mp) {
  int sc = blockIdx.x, b = blockIdx.y, tid = threadIdx.x;
  int d0 = tid * 4;
  float inv_mlen = lens[64 + b];
  float mlenf = lens[b];
  float s0 = 0, s1 = 0, s2 = 0, s3 = 0;
  for (int s = 0; s < 32; ++s) {
    int srow = sc * 32 + s;
    size_t row = (size_t)b * NS + srow;
    const float4 v = *(const float4*)(memory + row * ND + d0);
    s0 += v.x; s1 += v.y; s2 += v.z; s3 += v.w;
    float fs = (float)srow;
    float loc = (fs < mlenf) ? 1.0f - fs * inv_mlen : 1.0f;
    uint2 pk;
    pk.x = bfpack2(v.x * loc, v.y * loc);
    pk.y = bfpack2(v.z * loc, v.w * loc);
    *(uint2*)(mp + row * ND + d0) = pk;
  }
  float* p = v_s + b * ND + d0;
  atomicAdd(p + 0, s0 * inv_mlen);
  atomicAdd(p + 1, s1 * inv_mlen);
  atomicAdd(p + 2, s2 * inv_mlen);
  atomicAdd(p + 3, s3 * inv_mlen);
}

// ---------- ctx += partial([v_a;v_s] @ [W1_a;W1_s]): batched GEMV, 8 batches/block ----------
// grid (3 et x 8 bt x 8 dc); one W load feeds 8 batch-FMAs; W traffic 8x total (38 MB).
__global__ __launch_bounds__(256) void k_ctx(const float* __restrict__ W1,
                                             const float* __restrict__ v_a,
                                             const float* __restrict__ v_s,
                                             float* __restrict__ ctx) {
  int et = blockIdx.x, bt = blockIdx.y, dc = blockIdx.z, tid = threadIdx.x;
  __shared__ float vbuf[8][192];
  int b0 = bt * 8;
  for (int l = tid; l < 8 * 192; l += 256) {
    int bb = l / 192, jj = l % 192;
    int k = dc * 192 + jj;
    vbuf[bb][jj] = (k < ND) ? v_a[(b0 + bb) * ND + k] : v_s[(b0 + bb) * ND + (k - ND)];
  }
  __syncthreads();
  int e = et * 256 + tid;
  const float* Wk = W1 + (size_t)(ND + dc * 192) * ND + e;
  float acc[8] = {0.f, 0.f, 0.f, 0.f, 0.f, 0.f, 0.f, 0.f};
#pragma unroll 4
  for (int j = 0; j < 192; ++j) {
    float w = Wk[(size_t)j * ND];
#pragma unroll
    for (int bb = 0; bb < 8; ++bb) acc[bb] += vbuf[bb][j] * w;
  }
#pragma unroll
  for (int bb = 0; bb < 8; ++bb) atomicAdd(&ctx[(b0 + bb) * ND + e], acc[bb]);
}

// ---------- big GEMM: scores[row] += sum_e tanh((m'@W1_m)[row,e]+ctx+b1)*w2[e] ----------
// 128x128 block tile, BK=64, 4 waves (2x2 of 64x64), 16x16x32 bf16 MFMA.
// XCD-locality swizzle: bid = j*8 + xcd; XCD x owns rt in [32x,32x+32), et fastest,
// so the 6 et-sharers of each 196 KB A-tile hit the same XCD L2 back-to-back.
__global__ __launch_bounds__(256) void k_gemm_scores(const unsigned short* __restrict__ mp,
                                                     const unsigned short* __restrict__ w1mt,
                                                     const float* __restrict__ ctx,
                                                     const float* __restrict__ b1,
                                                     const float* __restrict__ w2,
                                                     float* __restrict__ scores) {
  __shared__ char lds[32768];
  char* ldsA = lds;
  char* ldsB = lds + 16384;
  const int tid = threadIdx.x;
  const int wave = tid >> 6, lane = tid & 63;
  const int bid = blockIdx.x;
  const int xcd = bid & 7, j = bid >> 3;
  const int et = j % 6;
  const int rt = xcd * 32 + j / 6;
  const int row0 = rt * 128, n0 = et * 128;
  const int b = row0 >> 9;  // 128 | 512: tile never crosses a batch
  const int wm = wave & 1, wn = wave >> 1;

  // staging: each issue = 64 lanes x 16 B = 8 rows x 8 chunks, swizzled source
  const int lrow = lane >> 3;
  const int qlog = (lane & 7) ^ lrow;
  const char* Abase = (const char*)mp + (size_t)(row0 + lrow) * (ND * 2) + qlog * 16;
  const char* Bbase = (const char*)w1mt + (size_t)(n0 + lrow) * (ND * 2) + qlog * 16;

  f32x4 acc[4][4];
#pragma unroll
  for (int i = 0; i < 4; ++i)
#pragma unroll
    for (int t = 0; t < 4; ++t) acc[i][t] = (f32x4){0.f, 0.f, 0.f, 0.f};

  const int q2 = lane >> 4, c = lane & 15;
  int offA0[4], offB0[4];
#pragma unroll
  for (int i = 0; i < 4; ++i) {
    int ml = wm * 64 + i * 16 + c;
    offA0[i] = ml * 128 + ((q2 ^ (ml & 7)) * 16);
    int nl = wn * 64 + i * 16 + c;
    offB0[i] = nl * 128 + ((q2 ^ (nl & 7)) * 16);
  }
  // kk=1 chunk: (q2+4)^(row&7) = (q2^(row&7))^4 -> byte offset ^ 64

  for (int kb = 0; kb < ND * 2; kb += 128) {  // 12 K-steps of 64 k (128 B/row)
#pragma unroll
    for (int i = 0; i < 4; ++i) {
      int g = wave * 4 + i;
      async_copy16(Abase + (size_t)g * 8 * (ND * 2) + kb, ldsA + g * 1024);
      async_copy16(Bbase + (size_t)g * 8 * (ND * 2) + kb, ldsB + g * 1024);
    }
    __syncthreads();
#pragma unroll
    for (int kk = 0; kk < 2; ++kk) {
      const int x = kk * 64;
      bf16x8 bfrag[4];
#pragma unroll
      for (int t = 0; t < 4; ++t) bfrag[t] = *(const bf16x8*)(ldsB + (offB0[t] ^ x));
#pragma unroll
      for (int i = 0; i < 4; ++i) {
        bf16x8 afrag = *(const bf16x8*)(ldsA + (offA0[i] ^ x));
#pragma unroll
        for (int t = 0; t < 4; ++t)
          acc[i][t] = __builtin_amdgcn_mfma_f32_16x16x32_bf16(afrag, bfrag[t], acc[i][t], 0, 0, 0);
      }
    }
    __syncthreads();
  }

  // epilogue: C/D tile layout row = q2*4+r, col = c
  float ctxv[4], w2v[4];
#pragma unroll
  for (int t = 0; t < 4; ++t) {
    int n = n0 + wn * 64 + t * 16 + c;
    ctxv[t] = ctx[b * ND + n] + b1[n];
    w2v[t] = w2[n];
  }
#pragma unroll
  for (int i = 0; i < 4; ++i) {
#pragma unroll
    for (int r = 0; r < 4; ++r) {
      float s = 0.f;
#pragma unroll
      for (int t = 0; t < 4; ++t) s += fast_tanh(acc[i][t][r] + ctxv[t]) * w2v[t];
      s += __shfl_xor(s, 1, 64);
      s += __shfl_xor(s, 2, 64);
      s += __shfl_xor(s, 4, 64);
      s += __shfl_xor(s, 8, 64);
      if (c == 0) atomicAdd(&scores[row0 + wm * 64 + i * 16 + q2 * 4 + r], s);
    }
  }
}

// ---------- fused softmax + v_ts: each block recomputes softmax stats, 32 rows ----------
__global__ __launch_bounds__(192) void k_vts_sm(const unsigned short* __restrict__ mp,
                                                const float* __restrict__ scores,
                                                float* __restrict__ v_ts) {
  int sc = blockIdx.x, b = blockIdx.y, tid = threadIdx.x;
  int wid = tid >> 6, lane = tid & 63;
  __shared__ float sm[3], ss[3];
  __shared__ float al[32];
  float v[3];
#pragma unroll
  for (int k = 0; k < 3; ++k) {
    int j = tid + k * 192;
    v[k] = (j < NS) ? scores[b * NS + j] : -1e30f;
  }
  float m = fmaxf(fmaxf(v[0], v[1]), v[2]);
  for (int off = 1; off < 64; off <<= 1) m = fmaxf(m, __shfl_xor(m, off, 64));
  if (lane == 0) sm[wid] = m;
  __syncthreads();
  float M = fmaxf(fmaxf(sm[0], sm[1]), sm[2]);
  float e = 0.f;
#pragma unroll
  for (int k = 0; k < 3; ++k)
    if (tid + k * 192 < NS) e += __expf(v[k] - M);
  for (int off = 1; off < 64; off <<= 1) e += __shfl_xor(e, off, 64);
  if (lane == 0) ss[wid] = e;
  __syncthreads();
  float invS = 1.0f / (ss[0] + ss[1] + ss[2]);
  if (tid < 32) al[tid] = __expf(scores[b * NS + sc * 32 + tid] - M) * invS;
  __syncthreads();

  int d0 = tid * 4;
  float a0 = 0, a1 = 0, a2 = 0, a3 = 0;
  for (int s = 0; s < 32; ++s) {
    size_t row = (size_t)b * NS + sc * 32 + s;
    uint2 pk = *(const uint2*)(mp + row * ND + d0);
    float a = al[s];
    a0 += a * __uint_as_float(pk.x << 16);
    a1 += a * __uint_as_float(pk.x & 0xFFFF0000u);
    a2 += a * __uint_as_float(pk.y << 16);
    a3 += a * __uint_as_float(pk.y & 0xFFFF0000u);
  }
  float* p = v_ts + b * ND + d0;
  atomicAdd(p + 0, a0);
  atomicAdd(p + 1, a1);
  atomicAdd(p + 2, a2);
  atomicAdd(p + 3, a3);
}

// ---------- u += partial((v_ts+v_s) @ Wm): batched GEMV, 8 batches/block ----------
__global__ __launch_bounds__(256) void k_final1(const float* __restrict__ v_ts,
                                                const float* __restrict__ v_s,
                                                const float* __restrict__ Wm,
                                                float* __restrict__ u) {
  int et = blockIdx.x, bt = blockIdx.y, dc = blockIdx.z, tid = threadIdx.x;
  __shared__ float vbuf[8][192];
  int b0 = bt * 8;
  for (int l = tid; l < 8 * 192; l += 256) {
    int bb = l / 192, jj = l % 192;
    int d = dc * 192 + jj;
    vbuf[bb][jj] = v_ts[(b0 + bb) * ND + d] + v_s[(b0 + bb) * ND + d];
  }
  __syncthreads();
  int e = et * 256 + tid;
  const float* Wk = Wm + (size_t)(dc * 192) * ND + e;
  float acc[8] = {0.f, 0.f, 0.f, 0.f, 0.f, 0.f, 0.f, 0.f};
#pragma unroll 4
  for (int j = 0; j < 192; ++j) {
    float w = Wk[(size_t)j * ND];
#pragma unroll
    for (int bb = 0; bb < 8; ++bb) acc[bb] += vbuf[bb][j] * w;
  }
#pragma unroll
  for (int bb = 0; bb < 8; ++bb) atomicAdd(&u[(b0 + bb) * ND + e], acc[bb]);
}

// ---------- logits = tanh(u+bm) @ Wd + bd ----------
__global__ __launch_bounds__(256) void k_final2(const float* __restrict__ u,
                                                const float* __restrict__ bm,
                                                const float* __restrict__ Wd,
                                                const float* __restrict__ bd,
                                                float* __restrict__ out) {
  int b = blockIdx.x, tid = threadIdx.x;
  int wid = tid >> 6, lane = tid & 63;
  __shared__ float red[4][3];
  float p0 = 0, p1 = 0, p2 = 0;
  for (int e = tid; e < ND; e += 256) {
    float vm = fast_tanh(u[b * ND + e] + bm[e]);
    p0 += vm * Wd[e * 3 + 0];
    p1 += vm * Wd[e * 3 + 1];
    p2 += vm * Wd[e * 3 + 2];
  }
  for (int off = 1; off < 64; off <<= 1) {
    p0 += __shfl_xor(p0, off, 64);
    p1 += __shfl_xor(p1, off, 64);
    p2 += __shfl_xor(p2, off, 64);
  }
  if (lane == 0) { red[wid][0] = p0; red[wid][1] = p1; red[wid][2] = p2; }
  __syncthreads();
  if (tid == 0) {
    out[b * 3 + 0] = red[0][0] + red[1][0] + red[2][0] + red[3][0] + bd[0];
    out[b * 3 + 1] = red[0][1] + red[1][1] + red[2][1] + red[3][1] + bd[1];
    out[b * 3 + 2] = red[0][2] + red[1][2] + red[2][2] + red[3][2] + bd[2];
  }
}

extern "C" void kernel_launch(void* const* d_in, const int* in_sizes, int n_in,
                              void* d_out, int out_size, void* d_ws, size_t ws_size,
                              hipStream_t stream) {
  const float* memory = (const float*)d_in[0];
  const float* aspect = (const float*)d_in[1];
  const int* ids = (const int*)d_in[2];
  const int* tids = (const int*)d_in[3];
  const float* W1 = (const float*)d_in[4];
  const float* b1 = (const float*)d_in[5];
  const float* w2 = (const float*)d_in[6];
  const float* Wm = (const float*)d_in[7];
  const float* bm = (const float*)d_in[8];
  const float* Wd = (const float*)d_in[9];
  const float* bd = (const float*)d_in[10];
  float* out = (float*)d_out;

  char* ws = (char*)d_ws;
  float* scores = (float*)(ws + OFF_SCORES);
  float* v_s = (float*)(ws + OFF_VS);
  float* v_ts = (float*)(ws + OFF_VTS);
  float* ctx = (float*)(ws + OFF_CTX);
  float* u = (float*)(ws + OFF_U);
  float* v_a = (float*)(ws + OFF_VA);
  float* lens = (float*)(ws + OFF_LENS);
  unsigned short* w1mt = (unsigned short*)(ws + OFF_W1MT);
  unsigned short* mp = (unsigned short*)(ws + OFF_MP);

  k_pre<<<864, 256, 0, stream>>>(W1, w1mt, ids, tids, aspect, v_a, lens, ws);
  k_vs_mprime<<<dim3(16, NB), 192, 0, stream>>>(memory, lens, v_s, mp);
  k_ctx<<<dim3(3, 8, 8), 256, 0, stream>>>(W1, v_a, v_s, ctx);
  k_gemm_scores<<<1536, 256, 0, stream>>>(mp, w1mt, ctx, b1, w2, scores);
  k_vts_sm<<<dim3(16, NB), 192, 0, stream>>>(mp, scores, v_ts);
  k_final1<<<dim3(3, 8, 4), 256, 0, stream>>>(v_ts, v_s, Wm, u);
  k_final2<<<NB, 256, 0, stream>>>(u, bm, Wd, bd, out);
}